// Round 9
// baseline (119.672 us; speedup 1.0000x reference)
//
#include <hip/hip_runtime.h>
#include <hip/hip_bf16.h>

#define SEQ 2048
#define HD 128
#define NH 32
#define NKV 8
#define ODIM 4096
#define QB 64
#define KVB 64
#define SCALE 0.08838834764831845f
#define NEGBIG -1e9f

typedef __attribute__((ext_vector_type(8))) short bf16x8;
typedef __attribute__((ext_vector_type(4))) float f32x4;

__device__ __forceinline__ unsigned short f2bf(float x) {
  union { __hip_bfloat16 b; unsigned short u; } c;
  c.b = __float2bfloat16(x);  // RNE, single HW cvt
  return c.u;
}

__device__ __forceinline__ unsigned pack2bf(float lo, float hi) {
  union { __hip_bfloat162 h; unsigned u; } c;
  c.h = __float22bfloat162_rn(float2{lo, hi});  // x=lo (low 16b), y=hi
  return c.u;
}

// GQA-fused: block = Q-tile pair {p, 31-p} x head-pair (2hp, 2hp+1), one KV
// stream. Each wave computes BOTH heads, reading each K/V^T LDS fragment once
// and issuing two MFMAs -> LDS read + staging traffic per FLOP halved.
// Swapped-operand MFMA: S^T = mfma(K, Q), O^T = mfma(V, P); lane owns one
// P-row per head; softmax stats scalar per head; P stays in registers.
__global__ __launch_bounds__(512, 2) void sdpa_flash_kernel(
    const float* __restrict__ q, const float* __restrict__ k,
    const float* __restrict__ v, float* __restrict__ out) {
  // LDS: K [64][128] bf16 swz (16KB) + V^T [128][64] bf16 swz (16KB)
  __shared__ __align__(16) unsigned char smem[32768];
  unsigned char* Klds = smem;
  unsigned char* Vlds = smem + 16384;
  const int tid = threadIdx.x;
  const int w = tid >> 6;
  const int l = tid & 63;
  const int lm = l & 15;
  const int lg = l >> 4;

  const int p = (int)blockIdx.x;       // 0..15 -> Q-tile pair {p, 31-p}
  const int hp = (int)blockIdx.y;      // 0..15 -> heads {2hp, 2hp+1}
  const int h0 = hp << 1;
  const int hkv = hp >> 1;             // kv head = (2hp)/4
  const int qtA = p;
  const int qtB = 31 - p;
  const int myqt = (w < 4) ? qtA : qtB;
  const int qbase = myqt * QB + 16 * (w & 3);
  const int myrow = qbase + lm;        // this lane's q row

  // ---- Q fragments for both heads, pre-scaled by 1/sqrt(D) ----
  // lane holds Q[q = lm][d = 32*c + 8*lg + j], j=0..7 contiguous
  bf16x8 qa[2][4];
  #pragma unroll
  for (int u = 0; u < 2; ++u) {
    const float* qr = q + ((size_t)((h0 + u) * SEQ + myrow)) * HD + 8 * lg;
    #pragma unroll
    for (int c = 0; c < 4; ++c) {
      float4 a = *(const float4*)(qr + 32 * c);
      float4 b = *(const float4*)(qr + 32 * c + 4);
      union { unsigned short hh[8]; bf16x8 vv; } pk;
      pk.hh[0] = f2bf(a.x * SCALE); pk.hh[1] = f2bf(a.y * SCALE);
      pk.hh[2] = f2bf(a.z * SCALE); pk.hh[3] = f2bf(a.w * SCALE);
      pk.hh[4] = f2bf(b.x * SCALE); pk.hh[5] = f2bf(b.y * SCALE);
      pk.hh[6] = f2bf(b.z * SCALE); pk.hh[7] = f2bf(b.w * SCALE);
      qa[u][c] = pk.vv;
    }
  }

  // O^T accumulators: o[u][nt2][i] = O_h[q=lm][d = 16*nt2 + 4*lg + i]
  f32x4 o[2][8];
  #pragma unroll
  for (int u = 0; u < 2; ++u)
    #pragma unroll
    for (int i = 0; i < 8; ++i) o[u][i] = (f32x4){0.f, 0.f, 0.f, 0.f};
  float mrow[2] = {-1e30f, -1e30f};
  float lrow[2] = {0.f, 0.f};

  const int ntiles = qtB + 1;  // union of both halves' needs
  const float* kg0 = k + (size_t)hkv * SEQ * HD;
  const float* vg0 = v + (size_t)hkv * SEQ * HD;

  for (int t = 0; t < ntiles; ++t) {
    const int kv0 = t * KVB;
    __syncthreads();  // previous tile's LDS reads complete

    // ---- stage K tile: [kv][d] bf16, b128 writes, XOR-swizzled ----
    {
      const float* kg = kg0 + (size_t)kv0 * HD;
      #pragma unroll
      for (int it = 0; it < 2; ++it) {
        int idx = it * 512 + tid;   // 0..1023
        int r = idx >> 4;           // kv row 0..63
        int c8 = (idx & 15) << 3;   // d start
        const float* src = kg + r * HD + c8;
        float4 a = *(const float4*)(src);
        float4 b = *(const float4*)(src + 4);
        union { unsigned short hh[8]; uint4 u4; } pk;
        pk.hh[0]=f2bf(a.x); pk.hh[1]=f2bf(a.y); pk.hh[2]=f2bf(a.z); pk.hh[3]=f2bf(a.w);
        pk.hh[4]=f2bf(b.x); pk.hh[5]=f2bf(b.y); pk.hh[6]=f2bf(b.z); pk.hh[7]=f2bf(b.w);
        int byte = (r << 8) + ((c8 << 1) ^ ((r & 7) << 4));
        *(uint4*)(Klds + byte) = pk.u4;
      }
      // ---- stage V^T: [d][kv] bf16, packed kv-pair b32 writes ----
      const float* vg = vg0 + (size_t)kv0 * HD;
      {
        int rr = (tid & 31) << 1;    // even kv row
        int db = tid >> 5;           // d-block 0..15
        const float* s0 = vg + rr * HD + (db << 3);
        const float* s1 = s0 + HD;
        float4 a0 = *(const float4*)(s0);
        float4 b0 = *(const float4*)(s0 + 4);
        float4 a1 = *(const float4*)(s1);
        float4 b1 = *(const float4*)(s1 + 4);
        float lo[8] = {a0.x,a0.y,a0.z,a0.w,b0.x,b0.y,b0.z,b0.w};
        float hi[8] = {a1.x,a1.y,a1.z,a1.w,b1.x,b1.y,b1.z,b1.w};
        #pragma unroll
        for (int j = 0; j < 8; ++j) {
          int d = (db << 3) + j;
          int byte = (d << 7) + ((rr << 1) ^ ((d & 7) << 4));
          *(unsigned*)(Vlds + byte) = pack2bf(lo[j], hi[j]);
        }
      }
    }
    __syncthreads();

    if (t <= myqt) {  // wave-uniform guard; A-waves idle past their diagonal
      // ---- S^T = K Q^T, both heads per K-fragment read ----
      // s[u][nt][i] = S_h[q=lm][kv = kv0 + 16*nt + 4*lg + i]
      f32x4 s[2][4];
      #pragma unroll
      for (int u = 0; u < 2; ++u)
        #pragma unroll
        for (int nt = 0; nt < 4; ++nt) s[u][nt] = (f32x4){0.f, 0.f, 0.f, 0.f};
      #pragma unroll
      for (int nt = 0; nt < 4; ++nt) {
        int r = (nt << 4) + lm;
        #pragma unroll
        for (int kc = 0; kc < 4; ++kc) {
          int byte = (r << 8) + (((kc << 6) + (lg << 4)) ^ ((r & 7) << 4));
          bf16x8 kb = *(const bf16x8*)(Klds + byte);
          s[0][nt] = __builtin_amdgcn_mfma_f32_16x16x32_bf16(kb, qa[0][kc], s[0][nt], 0, 0, 0);
          s[1][nt] = __builtin_amdgcn_mfma_f32_16x16x32_bf16(kb, qa[1][kc], s[1][nt], 0, 0, 0);
        }
      }

      // ---- causal mask (additive -1e9 like the reference) ----
      if (kv0 + KVB - 1 > qbase) {
        #pragma unroll
        for (int nt = 0; nt < 4; ++nt) {
          #pragma unroll
          for (int i = 0; i < 4; ++i) {
            int col = kv0 + (nt << 4) + (lg << 2) + i;
            float add = (col > myrow) ? NEGBIG : 0.f;
            s[0][nt][i] += add;
            s[1][nt][i] += add;
          }
        }
      }

      // ---- online softmax + in-register P B-frags, per head ----
      bf16x8 pb[2][2];
      #pragma unroll
      for (int u = 0; u < 2; ++u) {
        float tm = -1e30f;
        #pragma unroll
        for (int nt = 0; nt < 4; ++nt)
          #pragma unroll
          for (int i = 0; i < 4; ++i) tm = fmaxf(tm, s[u][nt][i]);
        tm = fmaxf(tm, __shfl_xor(tm, 16));
        tm = fmaxf(tm, __shfl_xor(tm, 32));
        float mn = fmaxf(mrow[u], tm);
        float fac = __expf(mrow[u] - mn);
        mrow[u] = mn;
        float rs = 0.f;
        #pragma unroll
        for (int nt = 0; nt < 4; ++nt) {
          #pragma unroll
          for (int i = 0; i < 4; ++i) {
            float pv = __expf(s[u][nt][i] - mn);
            s[u][nt][i] = pv;
            rs += pv;
          }
        }
        rs += __shfl_xor(rs, 16);
        rs += __shfl_xor(rs, 32);
        lrow[u] = lrow[u] * fac + rs;
        #pragma unroll
        for (int nt2 = 0; nt2 < 8; ++nt2)
          #pragma unroll
          for (int i = 0; i < 4; ++i) o[u][nt2][i] *= fac;

        // lane needs P[q=lm][kv = 32*kc + 8*lg + j], j=0..7
        unsigned pk0[4], pk1[4];
        #pragma unroll
        for (int nt = 0; nt < 4; ++nt) {
          pk0[nt] = pack2bf(s[u][nt][0], s[u][nt][1]);
          pk1[nt] = pack2bf(s[u][nt][2], s[u][nt][3]);
        }
        const int srcA = lm + ((lg & 1) << 5);  // lane group g_a = 2*(lg&1)
        const int srcB = srcA + 16;             // g_b = g_a + 1
        const bool lo2 = (lg < 2);
        #pragma unroll
        for (int kc = 0; kc < 2; ++kc) {
          int a0 = __shfl((int)pk0[2*kc], srcA), b0 = __shfl((int)pk0[2*kc+1], srcA);
          int a1 = __shfl((int)pk1[2*kc], srcA), b1 = __shfl((int)pk1[2*kc+1], srcA);
          int a2 = __shfl((int)pk0[2*kc], srcB), b2 = __shfl((int)pk0[2*kc+1], srcB);
          int a3 = __shfl((int)pk1[2*kc], srcB), b3 = __shfl((int)pk1[2*kc+1], srcB);
          union { int uu[4]; bf16x8 v; } pw;
          pw.uu[0] = lo2 ? a0 : b0;  // kv 8lg+{0,1}
          pw.uu[1] = lo2 ? a1 : b1;  // kv 8lg+{2,3}
          pw.uu[2] = lo2 ? a2 : b2;  // kv 8lg+{4,5}
          pw.uu[3] = lo2 ? a3 : b3;  // kv 8lg+{6,7}
          pb[u][kc] = pw.v;
        }
      }

      // ---- O^T += V^T P^T, both heads per V-fragment read ----
      #pragma unroll
      for (int nt2 = 0; nt2 < 8; ++nt2) {
        int dr = (nt2 << 4) + lm;
        #pragma unroll
        for (int kc = 0; kc < 2; ++kc) {
          int byte = (dr << 7) + (((kc << 6) + (lg << 4)) ^ ((dr & 7) << 4));
          bf16x8 vb = *(const bf16x8*)(Vlds + byte);
          o[0][nt2] = __builtin_amdgcn_mfma_f32_16x16x32_bf16(vb, pb[0][kc], o[0][nt2], 0, 0, 0);
          o[1][nt2] = __builtin_amdgcn_mfma_f32_16x16x32_bf16(vb, pb[1][kc], o[1][nt2], 0, 0, 0);
        }
      }
    }
  }

  // ---- epilogue: O /= l, coalesced float4 stores, both heads ----
  #pragma unroll
  for (int u = 0; u < 2; ++u) {
    float inv = 1.f / lrow[u];
    float* orow = out + (size_t)myrow * ODIM + (h0 + u) * HD + (lg << 2);
    #pragma unroll
    for (int nt2 = 0; nt2 < 8; ++nt2) {
      float4 st = {o[u][nt2][0] * inv, o[u][nt2][1] * inv,
                   o[u][nt2][2] * inv, o[u][nt2][3] * inv};
      *(float4*)(orow + (nt2 << 4)) = st;
    }
  }
}

extern "C" void kernel_launch(void* const* d_in, const int* in_sizes, int n_in,
                              void* d_out, int out_size, void* d_ws, size_t ws_size,
                              hipStream_t stream) {
  // inputs: [0]=input_pos(i64) [1]=q(f32) [2]=k(f32) [3]=v(f32)
  //         [4]=bsz [5]=seqlen [6]=mask(f32, pure causal -> computed analytically)
  const float* q = (const float*)d_in[1];
  const float* k = (const float*)d_in[2];
  const float* v = (const float*)d_in[3];
  float* out = (float*)d_out;
  dim3 grid(SEQ / QB / 2, NH / 2);  // 16 Q-tile pairs x 16 head-pairs = 256 blocks
  sdpa_flash_kernel<<<grid, 512, 0, stream>>>(q, k, v, out);
}